// Round 2
// baseline (138.125 us; speedup 1.0000x reference)
//
#include <hip/hip_runtime.h>
#include <math.h>

#define BATCH 32
#define SEQ   4096
#define HD    1024

// ---------------------------------------------------------------------------
// Fused score + online-softmax + weighted accumulate. Single HBM read of
// `values`. Rows are processed in PAIRS (one softmax rescale per pair,
// two interleaved shuffle-reduce chains), and pairs are software-pipelined
// one deep (loads of pair i+1 in flight while pair i runs its reduce chain).
// ---------------------------------------------------------------------------

struct RowPair {
    float4 a[4];   // row s   : lane holds h = k*256 + lane*4 + {0..3}
    float4 b[4];   // row s+1
    float  sa, sb; // scale[s], scale[s+1]
};

__device__ __forceinline__ void load_pair(const float* __restrict__ vb,
                                          const float* __restrict__ scale,
                                          int s, int lane, RowPair& rp)
{
    const float4* v4a = (const float4*)(vb + (size_t)s * HD);
    const float4* v4b = (const float4*)(vb + (size_t)(s + 1) * HD);
#pragma unroll
    for (int k = 0; k < 4; ++k) {
        rp.a[k] = v4a[k * 64 + lane];
        rp.b[k] = v4b[k * 64 + lane];
    }
    rp.sa = scale[s];
    rp.sb = scale[s + 1];
}

__device__ __forceinline__ void process_pair(const RowPair& rp,
                                             const float4* __restrict__ qf,
                                             float& m, float& l, float4* acc)
{
    float d0 = 0.f, d1 = 0.f;
#pragma unroll
    for (int k = 0; k < 4; ++k) {
        d0 += rp.a[k].x * qf[k].x + rp.a[k].y * qf[k].y
            + rp.a[k].z * qf[k].z + rp.a[k].w * qf[k].w;
        d1 += rp.b[k].x * qf[k].x + rp.b[k].y * qf[k].y
            + rp.b[k].z * qf[k].z + rp.b[k].w * qf[k].w;
    }
    // two butterfly chains, interleaved (independent -> latency overlaps)
#pragma unroll
    for (int off = 32; off >= 1; off >>= 1) {
        d0 += __shfl_xor(d0, off, 64);
        d1 += __shfl_xor(d1, off, 64);
    }
    const float sc0 = d0 * rp.sa;
    const float sc1 = d1 * rp.sb;
    const float mx  = fmaxf(sc0, sc1);
    if (mx <= m) {          // wave-uniform: no rescale needed (common case)
        const float p0 = __expf(sc0 - m);
        const float p1 = __expf(sc1 - m);
        l += p0 + p1;
#pragma unroll
        for (int k = 0; k < 4; ++k) {
            acc[k].x += p0 * rp.a[k].x + p1 * rp.b[k].x;
            acc[k].y += p0 * rp.a[k].y + p1 * rp.b[k].y;
            acc[k].z += p0 * rp.a[k].z + p1 * rp.b[k].z;
            acc[k].w += p0 * rp.a[k].w + p1 * rp.b[k].w;
        }
    } else {                // rescale (first pair: f = exp(-inf) = 0 zeroes acc)
        const float f  = __expf(m - mx);
        const float p0 = __expf(sc0 - mx);
        const float p1 = __expf(sc1 - mx);
        l = l * f + p0 + p1;
#pragma unroll
        for (int k = 0; k < 4; ++k) {
            acc[k].x = acc[k].x * f + p0 * rp.a[k].x + p1 * rp.b[k].x;
            acc[k].y = acc[k].y * f + p0 * rp.a[k].y + p1 * rp.b[k].y;
            acc[k].z = acc[k].z * f + p0 * rp.a[k].z + p1 * rp.b[k].z;
            acc[k].w = acc[k].w * f + p0 * rp.a[k].w + p1 * rp.b[k].w;
        }
        m = mx;
    }
}

template <int CPB>
__global__ __launch_bounds__(256, 4)   // pin VGPR<=128 -> 4 blocks/CU, no tail
void luong_pass1(const float* __restrict__ q,
                 const float* __restrict__ v,
                 const float* __restrict__ scale,
                 float* __restrict__ ws_acc,   // [BATCH*CPB][HD]
                 float* __restrict__ ws_m,     // [BATCH*CPB]
                 float* __restrict__ ws_l)     // [BATCH*CPB]
{
    constexpr int ROWS = SEQ / CPB;   // rows per block
    constexpr int RPW  = ROWS / 4;    // rows per wave
    constexpr int NP   = RPW / 2;     // pairs per wave (even, >=2 for CPB<=128)
    static_assert(NP >= 2 && (NP % 2) == 0, "pipeline needs even NP>=2");

    const int blk  = blockIdx.x;
    const int b    = blk / CPB;
    const int ch   = blk % CPB;
    const int tid  = threadIdx.x;
    const int wid  = tid >> 6;
    const int lane = tid & 63;

    const float4* q4 = (const float4*)(q + (size_t)b * HD);
    float4 qf[4];
#pragma unroll
    for (int k = 0; k < 4; ++k) qf[k] = q4[k * 64 + lane];

    float  m = -INFINITY, l = 0.f;
    float4 acc[4];
#pragma unroll
    for (int k = 0; k < 4; ++k) acc[k] = make_float4(0.f, 0.f, 0.f, 0.f);

    const int s0 = ch * ROWS + wid * RPW;
    const float* vb = v + (size_t)b * SEQ * HD;

    RowPair A, B;
    load_pair(vb, scale, s0, lane, A);
#pragma unroll 1
    for (int i = 0; i < NP - 2; i += 2) {
        load_pair(vb, scale, s0 + 2 * (i + 1), lane, B);
        process_pair(A, qf, m, l, acc);
        load_pair(vb, scale, s0 + 2 * (i + 2), lane, A);
        process_pair(B, qf, m, l, acc);
    }
    load_pair(vb, scale, s0 + 2 * (NP - 1), lane, B);
    process_pair(A, qf, m, l, acc);
    process_pair(B, qf, m, l, acc);

    // ---- combine the 4 waves of this block through LDS ----
    __shared__ float lds_m[4], lds_l[4];
    __shared__ float lds_acc[4][HD];
    if (lane == 0) { lds_m[wid] = m; lds_l[wid] = l; }
    __syncthreads();
    const float M  = fmaxf(fmaxf(lds_m[0], lds_m[1]), fmaxf(lds_m[2], lds_m[3]));
    const float fw = __expf(m - M);
    float4* la = (float4*)lds_acc[wid];
#pragma unroll
    for (int k = 0; k < 4; ++k) {
        float4 t;
        t.x = acc[k].x * fw; t.y = acc[k].y * fw;
        t.z = acc[k].z * fw; t.w = acc[k].w * fw;
        la[k * 64 + lane] = t;
    }
    __syncthreads();

    float lblk = 0.f;
#pragma unroll
    for (int w = 0; w < 4; ++w) lblk += lds_l[w] * __expf(lds_m[w] - M);

    const float4 a0 = ((const float4*)lds_acc[0])[tid];
    const float4 a1 = ((const float4*)lds_acc[1])[tid];
    const float4 a2 = ((const float4*)lds_acc[2])[tid];
    const float4 a3 = ((const float4*)lds_acc[3])[tid];
    float4 sum;
    sum.x = a0.x + a1.x + a2.x + a3.x;
    sum.y = a0.y + a1.y + a2.y + a3.y;
    sum.z = a0.z + a1.z + a2.z + a3.z;
    sum.w = a0.w + a1.w + a2.w + a3.w;
    ((float4*)(ws_acc + (size_t)blk * HD))[tid] = sum;
    if (tid == 0) { ws_m[blk] = M; ws_l[blk] = lblk; }
}

// ---------------------------------------------------------------------------
// Pass 2: combine the CPB partials of each batch and normalize. Tiny.
// ---------------------------------------------------------------------------
template <int CPB>
__global__ __launch_bounds__(256)
void luong_pass2(const float* __restrict__ ws_acc,
                 const float* __restrict__ ws_m,
                 const float* __restrict__ ws_l,
                 float* __restrict__ out)
{
    const int b   = blockIdx.x;
    const int tid = threadIdx.x;

    float M = -INFINITY;
#pragma unroll
    for (int i = 0; i < CPB; ++i) M = fmaxf(M, ws_m[b * CPB + i]);
    float T = 0.f;
#pragma unroll
    for (int i = 0; i < CPB; ++i) T += ws_l[b * CPB + i] * __expf(ws_m[b * CPB + i] - M);
    const float invT = 1.f / T;

    float4 sum = make_float4(0.f, 0.f, 0.f, 0.f);
#pragma unroll
    for (int i = 0; i < CPB; ++i) {
        const float wi = __expf(ws_m[b * CPB + i] - M) * invT;
        const float4 a = ((const float4*)(ws_acc + (size_t)(b * CPB + i) * HD))[tid];
        sum.x += wi * a.x; sum.y += wi * a.y;
        sum.z += wi * a.z; sum.w += wi * a.w;
    }
    ((float4*)(out + (size_t)b * HD))[tid] = sum;
}

// ---------------------------------------------------------------------------
template <int CPB>
static void launch_impl(const float* q, const float* v, const float* scale,
                        float* out, float* ws, hipStream_t stream)
{
    const int NB = BATCH * CPB;
    float* ws_acc = ws;
    float* ws_m   = ws + (size_t)NB * HD;
    float* ws_l   = ws_m + NB;
    luong_pass1<CPB><<<NB, 256, 0, stream>>>(q, v, scale, ws_acc, ws_m, ws_l);
    luong_pass2<CPB><<<BATCH, 256, 0, stream>>>(ws_acc, ws_m, ws_l, out);
}

extern "C" void kernel_launch(void* const* d_in, const int* in_sizes, int n_in,
                              void* d_out, int out_size, void* d_ws, size_t ws_size,
                              hipStream_t stream)
{
    const float* q     = (const float*)d_in[0];   // [B, H]
    const float* v     = (const float*)d_in[1];   // [B, S, H]
    const float* scale = (const float*)d_in[2];   // [S, 1]
    float* out = (float*)d_out;                   // [B, H]
    float* ws  = (float*)d_ws;

    int cpb = 32;
    while (cpb > 1 &&
           (size_t)BATCH * cpb * (HD + 2) * sizeof(float) > ws_size)
        cpb >>= 1;

    switch (cpb) {
        case 32: launch_impl<32>(q, v, scale, out, ws, stream); break;
        case 16: launch_impl<16>(q, v, scale, out, ws, stream); break;
        case 8:  launch_impl<8>(q, v, scale, out, ws, stream); break;
        case 4:  launch_impl<4>(q, v, scale, out, ws, stream); break;
        case 2:  launch_impl<2>(q, v, scale, out, ws, stream); break;
        default: launch_impl<1>(q, v, scale, out, ws, stream); break;
    }
}

// Round 5
// 101.140 us; speedup vs baseline: 1.3657x; 1.3657x over previous
//
#include <hip/hip_runtime.h>
#include <math.h>

#define BATCH 32
#define SEQ   4096
#define HD    1024

typedef float floatx4 __attribute__((ext_vector_type(4)));

// ---------------------------------------------------------------------------
// Fused score + online-softmax + weighted accumulate; single HBM read of
// `values`. vs R1: branchless softmax update (no wave-uniform branch in the
// loop -> compiler can schedule across rows), 1-row-deep A/B register
// pipeline (next row's 4 dwordx4 always in flight during the current row's
// dot/shuffle/exp/accum chain), non-temporal hints on the 512MB single-use
// stream, and per-wave scale[] hoisted into a lane register (when it fits).
// ---------------------------------------------------------------------------

__device__ __forceinline__ void load_row(const float* __restrict__ vb,
                                         int s, int lane, float4* vf)
{
    const floatx4* v4 = (const floatx4*)(vb + (size_t)s * HD);
#pragma unroll
    for (int k = 0; k < 4; ++k) {
        floatx4 t = __builtin_nontemporal_load(&v4[k * 64 + lane]);
        vf[k] = make_float4(t.x, t.y, t.z, t.w);
    }
}

__device__ __forceinline__ void process_row(const float4* vf,
                                            const float4* qf,
                                            float scale_r,
                                            float& m, float& l, float4* acc)
{
    float d = 0.f;
#pragma unroll
    for (int k = 0; k < 4; ++k)
        d += vf[k].x * qf[k].x + vf[k].y * qf[k].y
           + vf[k].z * qf[k].z + vf[k].w * qf[k].w;
#pragma unroll
    for (int off = 32; off >= 1; off >>= 1)
        d += __shfl_xor(d, off, 64);

    const float sc = d * scale_r;
    const float mn = fmaxf(m, sc);          // branchless online-softmax
    const float f  = __expf(m - mn);        // first row: exp(-inf)=0 zeroes acc
    const float p  = __expf(sc - mn);
    l = l * f + p;
#pragma unroll
    for (int k = 0; k < 4; ++k) {
        acc[k].x = acc[k].x * f + p * vf[k].x;
        acc[k].y = acc[k].y * f + p * vf[k].y;
        acc[k].z = acc[k].z * f + p * vf[k].z;
        acc[k].w = acc[k].w * f + p * vf[k].w;
    }
    m = mn;
}

template <int CPB>
__global__ __launch_bounds__(256)
void luong_pass1(const float* __restrict__ q,
                 const float* __restrict__ v,
                 const float* __restrict__ scale,
                 float* __restrict__ ws_acc,   // [BATCH*CPB][HD]
                 float* __restrict__ ws_m,     // [BATCH*CPB]
                 float* __restrict__ ws_l)     // [BATCH*CPB]
{
    constexpr int ROWS = SEQ / CPB;   // rows per block
    constexpr int RPW  = ROWS / 4;    // rows per wave (32 for CPB=32)
    static_assert(RPW >= 4 && (RPW % 2) == 0, "pipeline shape");

    const int blk  = blockIdx.x;
    const int b    = blk / CPB;
    const int ch   = blk % CPB;
    const int tid  = threadIdx.x;
    const int wid  = tid >> 6;
    const int lane = tid & 63;

    const float4* q4 = (const float4*)(q + (size_t)b * HD);
    float4 qf[4];
#pragma unroll
    for (int k = 0; k < 4; ++k) qf[k] = q4[k * 64 + lane];

    const int s0 = ch * ROWS + wid * RPW;
    const float* vb = v + (size_t)b * SEQ * HD;

    // hoist this wave's scale values when they fit one lane-register each:
    // lane r holds scale[s0+r] (r < RPW). Fallback (large RPW, only in the
    // small-CPB workspace-fallback paths): plain load per row.
    float scl = 0.f;
    if constexpr (RPW <= 64) {
        scl = (lane < RPW) ? scale[s0 + lane] : 0.f;
    }
    auto get_scale = [&](int r) -> float {
        if constexpr (RPW <= 64) return __shfl(scl, r, 64);
        else                     return scale[s0 + r];
    };

    float  m = -INFINITY, l = 0.f;
    float4 acc[4];
#pragma unroll
    for (int k = 0; k < 4; ++k) acc[k] = make_float4(0.f, 0.f, 0.f, 0.f);

    float4 va[4], vbuf[4];
    load_row(vb, s0, lane, va);
#pragma unroll 1
    for (int r = 0; r < RPW - 2; r += 2) {
        load_row(vb, s0 + r + 1, lane, vbuf);
        process_row(va, qf, get_scale(r), m, l, acc);
        load_row(vb, s0 + r + 2, lane, va);
        process_row(vbuf, qf, get_scale(r + 1), m, l, acc);
    }
    load_row(vb, s0 + RPW - 1, lane, vbuf);
    process_row(va, qf, get_scale(RPW - 2), m, l, acc);
    process_row(vbuf, qf, get_scale(RPW - 1), m, l, acc);

    // ---- combine the 4 waves of this block through LDS ----
    __shared__ float lds_m[4], lds_l[4];
    __shared__ float lds_acc[4][HD];
    if (lane == 0) { lds_m[wid] = m; lds_l[wid] = l; }
    __syncthreads();
    const float M  = fmaxf(fmaxf(lds_m[0], lds_m[1]), fmaxf(lds_m[2], lds_m[3]));
    const float fw = __expf(m - M);
    float4* la = (float4*)lds_acc[wid];
#pragma unroll
    for (int k = 0; k < 4; ++k) {
        float4 t;
        t.x = acc[k].x * fw; t.y = acc[k].y * fw;
        t.z = acc[k].z * fw; t.w = acc[k].w * fw;
        la[k * 64 + lane] = t;
    }
    __syncthreads();

    float lblk = 0.f;
#pragma unroll
    for (int w = 0; w < 4; ++w) lblk += lds_l[w] * __expf(lds_m[w] - M);

    const float4 a0 = ((const float4*)lds_acc[0])[tid];
    const float4 a1 = ((const float4*)lds_acc[1])[tid];
    const float4 a2 = ((const float4*)lds_acc[2])[tid];
    const float4 a3 = ((const float4*)lds_acc[3])[tid];
    float4 sum;
    sum.x = a0.x + a1.x + a2.x + a3.x;
    sum.y = a0.y + a1.y + a2.y + a3.y;
    sum.z = a0.z + a1.z + a2.z + a3.z;
    sum.w = a0.w + a1.w + a2.w + a3.w;
    ((float4*)(ws_acc + (size_t)blk * HD))[tid] = sum;
    if (tid == 0) { ws_m[blk] = M; ws_l[blk] = lblk; }
}

// ---------------------------------------------------------------------------
// Pass 2: combine the CPB partials of each batch and normalize. Tiny.
// ---------------------------------------------------------------------------
template <int CPB>
__global__ __launch_bounds__(256)
void luong_pass2(const float* __restrict__ ws_acc,
                 const float* __restrict__ ws_m,
                 const float* __restrict__ ws_l,
                 float* __restrict__ out)
{
    const int b   = blockIdx.x;
    const int tid = threadIdx.x;

    float M = -INFINITY;
#pragma unroll
    for (int i = 0; i < CPB; ++i) M = fmaxf(M, ws_m[b * CPB + i]);
    float T = 0.f;
#pragma unroll
    for (int i = 0; i < CPB; ++i) T += ws_l[b * CPB + i] * __expf(ws_m[b * CPB + i] - M);
    const float invT = 1.f / T;

    float4 sum = make_float4(0.f, 0.f, 0.f, 0.f);
#pragma unroll
    for (int i = 0; i < CPB; ++i) {
        const float wi = __expf(ws_m[b * CPB + i] - M) * invT;
        const float4 a = ((const float4*)(ws_acc + (size_t)(b * CPB + i) * HD))[tid];
        sum.x += wi * a.x; sum.y += wi * a.y;
        sum.z += wi * a.z; sum.w += wi * a.w;
    }
    ((float4*)(out + (size_t)b * HD))[tid] = sum;
}

// ---------------------------------------------------------------------------
template <int CPB>
static void launch_impl(const float* q, const float* v, const float* scale,
                        float* out, float* ws, hipStream_t stream)
{
    const int NB = BATCH * CPB;
    float* ws_acc = ws;
    float* ws_m   = ws + (size_t)NB * HD;
    float* ws_l   = ws_m + NB;
    luong_pass1<CPB><<<NB, 256, 0, stream>>>(q, v, scale, ws_acc, ws_m, ws_l);
    luong_pass2<CPB><<<BATCH, 256, 0, stream>>>(ws_acc, ws_m, ws_l, out);
}

extern "C" void kernel_launch(void* const* d_in, const int* in_sizes, int n_in,
                              void* d_out, int out_size, void* d_ws, size_t ws_size,
                              hipStream_t stream)
{
    const float* q     = (const float*)d_in[0];   // [B, H]
    const float* v     = (const float*)d_in[1];   // [B, S, H]
    const float* scale = (const float*)d_in[2];   // [S, 1]
    float* out = (float*)d_out;                   // [B, H]
    float* ws  = (float*)d_ws;

    int cpb = 32;
    while (cpb > 1 &&
           (size_t)BATCH * cpb * (HD + 2) * sizeof(float) > ws_size)
        cpb >>= 1;

    switch (cpb) {
        case 32: launch_impl<32>(q, v, scale, out, ws, stream); break;
        case 16: launch_impl<16>(q, v, scale, out, ws, stream); break;
        case 8:  launch_impl<8>(q, v, scale, out, ws, stream); break;
        case 4:  launch_impl<4>(q, v, scale, out, ws, stream); break;
        case 2:  launch_impl<2>(q, v, scale, out, ws, stream); break;
        default: launch_impl<1>(q, v, scale, out, ws, stream); break;
    }
}